// Round 3
// baseline (3490.825 us; speedup 1.0000x reference)
//
#include <hip/hip_runtime.h>
#include <stdint.h>

#define BATCH 32
#define SEQ   512
#define EDIM  512
#define HID   512            // per-direction hidden
#define NG    2048           // 4*HID gate rows
#define NTAG  16

typedef _Float16 f16;
typedef _Float16 f16x4 __attribute__((ext_vector_type(4)));
typedef _Float16 f16x8 __attribute__((ext_vector_type(8)));
typedef float    f32x4 __attribute__((ext_vector_type(4)));

#define LO_SCALE 2048.0f
#define LO_INV   (1.0f/2048.0f)

// ---------------- prep: fp32 -> f16 hi/lo limb split (lo scaled by 2048) ---
__global__ __launch_bounds__(256) void k_split(const float* __restrict__ src,
                                               f16* __restrict__ hi, f16* __restrict__ lo, int n) {
    int i = blockIdx.x * blockDim.x + threadIdx.x;
    int stride = gridDim.x * blockDim.x;
    for (; i < n; i += stride) {
        float x = src[i];
        f16 h = (f16)x;
        hi[i] = h;
        lo[i] = (f16)((x - (float)h) * LO_SCALE);
    }
}

// ---------------- gather embedding rows + split -----------------------------
__global__ __launch_bounds__(256) void k_gather(const int* __restrict__ sent,
                                                const float* __restrict__ emb,
                                                f16* __restrict__ ehi, f16* __restrict__ elo) {
    int m = blockIdx.x;                  // 0..16383 = b*SEQ+s
    int idx = sent[m];
    const float* src = emb + (size_t)idx * EDIM;
    int k = threadIdx.x * 2;
    float2 v = *(const float2*)(src + k);
    f16 h0 = (f16)v.x, h1 = (f16)v.y;
    ehi[(size_t)m*EDIM + k]     = h0;
    ehi[(size_t)m*EDIM + k + 1] = h1;
    elo[(size_t)m*EDIM + k]     = (f16)((v.x - (float)h0) * LO_SCALE);
    elo[(size_t)m*EDIM + k + 1] = (f16)((v.y - (float)h1) * LO_SCALE);
}

__device__ __forceinline__ void gld16(const void* g, void* l) {
    __builtin_amdgcn_global_load_lds((const __attribute__((address_space(1))) uint32_t*)g,
                                     (__attribute__((address_space(3))) uint32_t*)l, 16, 0, 0);
}
__device__ __forceinline__ f32x4 mfma16(f16x8 a, f16x8 b, f32x4 c) {
    return __builtin_amdgcn_mfma_f32_16x16x32_f16(a, b, c, 0, 0, 0);
}

// ---------------- input projection: X = emb @ Wih^T + bias (f16x2 limbs) ----
__global__ __launch_bounds__(512, 2) void k_gemm(
    const f16* __restrict__ Ahi, const f16* __restrict__ Alo,    // [16384][512]
    const f16* __restrict__ Whi, const f16* __restrict__ Wlo,    // [2][2048][512]
    const float* __restrict__ bias_f, const float* __restrict__ bias_b,
    float* __restrict__ Xout)                                     // [2][16384][2048]
{
    const int n0  = blockIdx.x * 128;
    const int m0  = blockIdx.y * 128;
    const int dir = blockIdx.z;
    const float* bias = dir ? bias_b : bias_f;
    const f16* Bhi = Whi + (size_t)dir * NG * EDIM;
    const f16* Blo = Wlo + (size_t)dir * NG * EDIM;
    float* X = Xout + (size_t)dir * 16384 * NG;

    __shared__ f16 sAh[128*64], sAl[128*64], sBh[128*64], sBl[128*64];  // 64 KiB

    const int tid  = threadIdx.x;
    const int lane = tid & 63;
    const int wave = tid >> 6;        // 0..7
    const int wr   = wave >> 2;       // 0..1  (64 rows)
    const int wc   = wave & 3;        // 0..3  (32 cols)

    f32x4 accH[4][2] = {};
    f32x4 accM[4][2] = {};

    for (int kt = 0; kt < 8; ++kt) {
        const int kbase = kt * 64;
        for (int sub = 0; sub < 2; ++sub) {
            int byte = sub*8192 + tid*16;
            int row  = byte >> 7;          // 0..127
            int up   = (byte >> 4) & 7;
            int u    = up ^ (row & 7);     // logical 16B unit
            const f16* ga  = Ahi + (size_t)(m0 + row)*EDIM + kbase + u*8;
            const f16* gal = Alo + (size_t)(m0 + row)*EDIM + kbase + u*8;
            const f16* gb  = Bhi + (size_t)(n0 + row)*EDIM + kbase + u*8;
            const f16* gbl = Blo + (size_t)(n0 + row)*EDIM + kbase + u*8;
            gld16(ga,  (char*)sAh + byte);
            gld16(gal, (char*)sAl + byte);
            gld16(gb,  (char*)sBh + byte);
            gld16(gbl, (char*)sBl + byte);
        }
        __syncthreads();
        for (int ks = 0; ks < 2; ++ks) {
            f16x8 fAh[4], fAl[4], fBh[2], fBl[2];
            #pragma unroll
            for (int mi = 0; mi < 4; ++mi) {
                int row = wr*64 + mi*16 + (lane & 15);
                int u   = ks*4 + (lane >> 4);
                int off = row*128 + (u ^ (row & 7))*16;
                fAh[mi] = *(const f16x8*)((const char*)sAh + off);
                fAl[mi] = *(const f16x8*)((const char*)sAl + off);
            }
            #pragma unroll
            for (int ni = 0; ni < 2; ++ni) {
                int row = wc*32 + ni*16 + (lane & 15);
                int u   = ks*4 + (lane >> 4);
                int off = row*128 + (u ^ (row & 7))*16;
                fBh[ni] = *(const f16x8*)((const char*)sBh + off);
                fBl[ni] = *(const f16x8*)((const char*)sBl + off);
            }
            #pragma unroll
            for (int mi = 0; mi < 4; ++mi)
                #pragma unroll
                for (int ni = 0; ni < 2; ++ni)
                    accH[mi][ni] = mfma16(fAh[mi], fBh[ni], accH[mi][ni]);
            #pragma unroll
            for (int mi = 0; mi < 4; ++mi)
                #pragma unroll
                for (int ni = 0; ni < 2; ++ni)
                    accM[mi][ni] = mfma16(fAh[mi], fBl[ni], accM[mi][ni]);
            #pragma unroll
            for (int mi = 0; mi < 4; ++mi)
                #pragma unroll
                for (int ni = 0; ni < 2; ++ni)
                    accM[mi][ni] = mfma16(fAl[mi], fBh[ni], accM[mi][ni]);
        }
        __syncthreads();
    }
    #pragma unroll
    for (int ni = 0; ni < 2; ++ni) {
        int col = n0 + wc*32 + ni*16 + (lane & 15);
        float bv = bias[col];
        #pragma unroll
        for (int mi = 0; mi < 4; ++mi) {
            #pragma unroll
            for (int j = 0; j < 4; ++j) {
                int m = m0 + wr*64 + mi*16 + (lane >> 4)*4 + j;
                X[(size_t)m * NG + col] = accH[mi][ni][j] + accM[mi][ni][j]*LO_INV + bv;
            }
        }
    }
}

// ---------------- persistent bidirectional LSTM recurrence (v3) -------------
// 64 WGs: dir(2) x chunk(32, 16 hidden units => 64 gate rows).
// LDS: [0,64K) Whh-hi slice; [64K,96K) h-hi plane; [96K,128K) h-lo plane;
//      [128K,+) gbuf[4][32][17].
// Whh-lo B-fragments live in registers (step-invariant, 64 VGPR).
// Sync: per-WG epoch flags (128-B padded), sc1 store + parallel 32-lane poll.
__global__ __launch_bounds__(512, 1) void k_rec(
    const float* __restrict__ Xall,                               // [2][16384][2048]
    const f16* __restrict__ Whi, const f16* __restrict__ Wlo,     // [2][2048][512]
    float* __restrict__ hx,                                       // [2][2][32][512] f32
    float* __restrict__ h_hist,                                   // [16384][1024]
    unsigned int* __restrict__ cnt)                               // [2][32][32] epoch flags
{
    extern __shared__ char smem[];
    char*  whiS = smem;                       // Whh-hi slice, swizzled
    char*  hhiS = smem + 65536;               // h hi plane [32][64][16B] swizzled
    char*  hloS = smem + 98304;               // h lo plane
    float* gbuf = (float*)(smem + 131072);    // [4][32][17]

    const int wg    = blockIdx.x;
    const int dir   = wg >> 5;
    const int chunk = wg & 31;
    const int u0    = chunk * 16;
    const int tid   = threadIdx.x;
    const int lane  = tid & 63;
    const int wave  = tid >> 6;
    const int g     = wave >> 1;     // gate type i,f,g,o
    const int mt    = wave & 1;      // batch half

    const float* X = Xall + (size_t)dir * 16384 * NG;
    float* hxd = hx + (size_t)dir * 2 * BATCH * HID;
    unsigned int* myflag   = cnt + (dir*32 + chunk) * 32;
    unsigned int* dirflags = cnt + dir*32*32;

    // fill Whh-hi slice (swizzled): rows 0..63 = 4 gates x 16 hidden units
    for (int n = tid; n < 4096; n += 512) {   // 16B units: 64 rows x 64 units
        int row = n >> 6;
        int u   = n & 63;
        int grow = (row >> 4)*512 + u0 + (row & 15);
        const f16* src = Whi + ((size_t)(dir*NG + grow))*EDIM + u*8;
        *(uint4*)(whiS + row*1024 + (u ^ (row & 7))*16) = *(const uint4*)src;
    }

    float c = 0.0f;                   // cell state for (pb,pu)
    const int pb = tid >> 4;          // batch 0..31
    const int pu = tid & 15;          // hidden unit within chunk
    const int r  = g*16 + (lane & 15);
    const char* WrowH = whiS + r*1024;
    const int arow  = mt*16 + (lane & 15);
    const char* hrowH = hhiS + arow*1024;
    const char* hrowL = hloS + arow*1024;
    const int arow7 = arow & 7;
    const int r7    = r & 7;

    // Whh-lo B-fragments: step-invariant -> registers (64 VGPR)
    const f16* bloP = Wlo + ((size_t)(dir*NG + g*512 + u0 + (lane & 15)))*EDIM;
    f16x8 blv[16];
    #pragma unroll
    for (int kt = 0; kt < 16; ++kt)
        blv[kt] = *(const f16x8*)(bloP + kt*32 + (lane >> 4)*8);

    __syncthreads();

    for (int t = 0; t < SEQ; ++t) {
        const int s = dir ? (SEQ - 1 - t) : t;

        // X prefetch (latency hides under sync wait)
        float xv[4];
        {
            int col = g*512 + u0 + (lane & 15);
            #pragma unroll
            for (int j = 0; j < 4; ++j) {
                int batch = mt*16 + (lane >> 4)*4 + j;
                xv[j] = X[((size_t)batch*SEQ + s)*NG + col];
            }
        }

        if (t > 0) {
            if (wave == 0) {
                unsigned int* fl = dirflags + (lane & 31)*32;
                const unsigned tgt = (unsigned)t;
                for (;;) {
                    unsigned v = __hip_atomic_load(fl, __ATOMIC_RELAXED, __HIP_MEMORY_SCOPE_AGENT);
                    if (__all(v >= tgt)) break;
                    __builtin_amdgcn_s_sleep(1);
                }
            }
            __syncthreads();
        }

        // load h_t (f32, coherence-point reads) -> split limbs -> LDS planes
        {
            const float* hsrc = hxd + (size_t)(t & 1) * BATCH * HID;
            #pragma unroll
            for (int i = 0; i < 8; ++i) {
                int q     = i*512 + tid;        // quad of f32, 0..4095
                int batch = q >> 7;             // 128 quads per batch row
                int kq    = (q & 127) * 4;      // unit index 0..508
                const float* p = hsrc + batch*512 + kq;
                unsigned long long a = __hip_atomic_load((const unsigned long long*)p,
                                          __ATOMIC_RELAXED, __HIP_MEMORY_SCOPE_AGENT);
                unsigned long long b = __hip_atomic_load((const unsigned long long*)(p + 2),
                                          __ATOMIC_RELAXED, __HIP_MEMORY_SCOPE_AGENT);
                float f0 = __builtin_bit_cast(float, (unsigned int)a);
                float f1 = __builtin_bit_cast(float, (unsigned int)(a >> 32));
                float f2 = __builtin_bit_cast(float, (unsigned int)b);
                float f3 = __builtin_bit_cast(float, (unsigned int)(b >> 32));
                f16 h0 = (f16)f0, h1 = (f16)f1, h2 = (f16)f2, h3 = (f16)f3;
                f16x4 vh = {h0, h1, h2, h3};
                f16x4 vl = {(f16)((f0 - (float)h0) * LO_SCALE),
                            (f16)((f1 - (float)h1) * LO_SCALE),
                            (f16)((f2 - (float)h2) * LO_SCALE),
                            (f16)((f3 - (float)h3) * LO_SCALE)};
                int off = batch*1024 + (((kq >> 3) ^ (batch & 7)))*16 + (kq & 7)*2;
                *(f16x4*)(hhiS + off) = vh;
                *(f16x4*)(hloS + off) = vl;
            }
        }
        __syncthreads();

        // MFMA: gates = h @ Whh^T (+X preloaded into acc)
        f32x4 aH[2], aMa[2], aMb[2];
        aH[0] = (f32x4){xv[0], xv[1], xv[2], xv[3]};
        aH[1] = (f32x4){0.f, 0.f, 0.f, 0.f};
        aMa[0] = aH[1]; aMa[1] = aH[1]; aMb[0] = aH[1]; aMb[1] = aH[1];
        #pragma unroll
        for (int kt = 0; kt < 16; ++kt) {
            int ug = kt*4 + (lane >> 4);
            f16x8 ah = *(const f16x8*)(hrowH + (ug ^ arow7)*16);
            f16x8 al = *(const f16x8*)(hrowL + (ug ^ arow7)*16);
            f16x8 bh = *(const f16x8*)(WrowH + (ug ^ r7)*16);
            aH [kt & 1] = mfma16(ah, bh, aH [kt & 1]);
            aMa[kt & 1] = mfma16(ah, blv[kt], aMa[kt & 1]);
            aMb[kt & 1] = mfma16(al, bh, aMb[kt & 1]);
        }
        f32x4 rH = aH[0] + aH[1];
        f32x4 rM = aMa[0] + aMa[1] + aMb[0] + aMb[1];
        #pragma unroll
        for (int j = 0; j < 4; ++j) {
            int batch = mt*16 + (lane >> 4)*4 + j;
            gbuf[(g*BATCH + batch)*17 + (lane & 15)] = rH[j] + rM[j]*LO_INV;
        }
        __syncthreads();

        // pointwise LSTM cell
        float hval;
        {
            float iv = gbuf[(0*BATCH + pb)*17 + pu];
            float fv = gbuf[(1*BATCH + pb)*17 + pu];
            float gv = gbuf[(2*BATCH + pb)*17 + pu];
            float ov = gbuf[(3*BATCH + pb)*17 + pu];
            float si = 1.0f / (1.0f + expf(-iv));
            float sf = 1.0f / (1.0f + expf(-fv));
            float so = 1.0f / (1.0f + expf(-ov));
            c = sf * c + si * tanhf(gv);
            hval = so * tanhf(c);
            float* hdst = hxd + (size_t)((t + 1) & 1)*BATCH*HID + pb*HID + u0 + pu;
            __hip_atomic_store(hdst, hval, __ATOMIC_RELAXED, __HIP_MEMORY_SCOPE_AGENT);
        }
        __syncthreads();   // every thread's sc1 h-store retired (vmcnt 0) before flag
        if (tid == 0)
            __hip_atomic_store(myflag, (unsigned)(t + 1), __ATOMIC_RELAXED, __HIP_MEMORY_SCOPE_AGENT);
        // h_hist off the critical path: drains during next step's poll
        h_hist[((size_t)pb*SEQ + s)*1024 + dir*HID + u0 + pu] = hval;
    }
}

// ---------------- output projection: feats = H @ W_out^T + b_out ------------
__global__ __launch_bounds__(256) void k_feats(
    const float* __restrict__ H,      // [16384][1024]
    const float* __restrict__ Wout,   // [16][1024]
    const float* __restrict__ bout,   // [16]
    float* __restrict__ feats)        // [16384][16]
{
    __shared__ float Wt[1024][16];    // 64 KiB, transposed
    int tid = threadIdx.x;
    for (int i = tid; i < 16384; i += 256)
        Wt[i >> 4][i & 15] = Wout[(i & 15)*1024 + (i >> 4)];
    __syncthreads();
    int wave = tid >> 6, lane = tid & 63;
    int row = blockIdx.x * 4 + wave;
    const float* hrow = H + (size_t)row * 1024;
    float acc[16];
    #pragma unroll
    for (int t = 0; t < 16; ++t) acc[t] = 0.f;
    #pragma unroll
    for (int cc = 0; cc < 4; ++cc) {
        float4 hv = *(const float4*)(hrow + cc*256 + lane*4);
        #pragma unroll
        for (int j = 0; j < 4; ++j) {
            int k = cc*256 + lane*4 + j;
            float h = (&hv.x)[j];
            #pragma unroll
            for (int tg = 0; tg < 16; ++tg) acc[tg] += h * Wt[k][tg];
        }
    }
    #pragma unroll
    for (int off = 32; off >= 1; off >>= 1) {
        #pragma unroll
        for (int tg = 0; tg < 16; ++tg) acc[tg] += __shfl_xor(acc[tg], off);
    }
    if (lane == 0) {
        #pragma unroll
        for (int tg = 0; tg < 16; ++tg)
            feats[(size_t)row*16 + tg] = acc[tg] + bout[tg];
    }
}

// ---------------- Viterbi + backtrace (one wave per batch) ------------------
__global__ __launch_bounds__(64) void k_viterbi(
    const float* __restrict__ feats,   // [32][512][16]
    const float* __restrict__ trans,   // [16][16] trans[prev][cur]
    const float* __restrict__ startt, const float* __restrict__ stopt,
    int* __restrict__ out)             // [32][512]
{
    __shared__ unsigned char bp[511*16];
    int b = blockIdx.x;
    int lane = threadIdx.x;
    int cur = lane & 15;
    int q   = lane >> 4;
    float tr[4];
    #pragma unroll
    for (int i = 0; i < 4; ++i) tr[i] = trans[(q*4 + i)*16 + cur];
    const float* fb = feats + (size_t)b * SEQ * NTAG;
    float v = fb[cur] + startt[cur];
    for (int s = 1; s < SEQ; ++s) {
        float best = -1e30f; int bi = 0;
        #pragma unroll
        for (int i = 0; i < 4; ++i) {
            float pv = __shfl(v, q*4 + i);
            float sc = pv + tr[i];
            if (sc > best) { best = sc; bi = q*4 + i; }   // first-max within quarter
        }
        #pragma unroll
        for (int off = 16; off <= 32; off <<= 1) {
            float ob = __shfl_xor(best, off);
            int   oi = __shfl_xor(bi, off);
            if (ob > best || (ob == best && oi < bi)) { best = ob; bi = oi; }
        }
        if (lane < 16) bp[(s - 1)*16 + cur] = (unsigned char)bi;
        v = best + fb[s*16 + cur];
    }
    float sc = v + stopt[cur];
    int bc = cur;
    #pragma unroll
    for (int off = 1; off <= 32; off <<= 1) {
        float os = __shfl_xor(sc, off);
        int   oc = __shfl_xor(bc, off);
        if (os > sc || (os == sc && oc < bc)) { sc = os; bc = oc; }
    }
    __syncthreads();
    if (lane == 0) {
        int curt = bc;
        out[b*SEQ + SEQ - 1] = curt;
        for (int s2 = SEQ - 2; s2 >= 0; --s2) {
            curt = bp[s2*16 + curt];
            out[b*SEQ + s2] = curt;
        }
    }
}

// ---------------- launch ----------------------------------------------------
extern "C" void kernel_launch(void* const* d_in, const int* in_sizes, int n_in,
                              void* d_out, int out_size, void* d_ws, size_t ws_size,
                              hipStream_t stream) {
    (void)in_sizes; (void)n_in; (void)out_size; (void)ws_size;
    const int*   sentence  = (const int*)  d_in[0];
    const float* embedding = (const float*)d_in[1];
    const float* Wih_f = (const float*)d_in[2];
    const float* Whh_f = (const float*)d_in[3];
    const float* b_f   = (const float*)d_in[4];
    const float* Wih_b = (const float*)d_in[5];
    const float* Whh_b = (const float*)d_in[6];
    const float* b_b   = (const float*)d_in[7];
    const float* W_out = (const float*)d_in[8];
    const float* b_out = (const float*)d_in[9];
    const float* trans = (const float*)d_in[10];
    const float* startt= (const float*)d_in[11];
    const float* stopt = (const float*)d_in[12];

    char* ws = (char*)d_ws;
    float* X      = (float*)(ws);                           // 268,435,456 B  [2][16384][2048]
    float* h_hist = (float*)(ws + 268435456ull);            //  67,108,864 B  [16384][1024]
    f16*   ehi    = (f16*)  (ws + 335544320ull);            //  16,777,216 B
    f16*   elo    = (f16*)  (ws + 352321536ull);            //  16,777,216 B
    f16*   wihhi  = (f16*)  (ws + 369098752ull);            //   4,194,304 B
    f16*   wihlo  = (f16*)  (ws + 373293056ull);
    f16*   whhhi  = (f16*)  (ws + 377487360ull);
    f16*   whhlo  = (f16*)  (ws + 381681664ull);
    float* hx     = (float*)(ws + 385875968ull);            //     262,144 B  [2][2][32][512]
    float* feats  = (float*)(ws + 386138112ull);            //   1,048,576 B
    unsigned int* cnt = (unsigned int*)(ws + 387186688ull); //       8,192 B  epoch flags

    hipMemsetAsync(cnt, 0, 8192,   stream);
    hipMemsetAsync(hx,  0, 262144, stream);

    k_split<<<1024, 256, 0, stream>>>(Wih_f, wihhi,          wihlo,          NG*EDIM);
    k_split<<<1024, 256, 0, stream>>>(Wih_b, wihhi + NG*EDIM, wihlo + NG*EDIM, NG*EDIM);
    k_split<<<1024, 256, 0, stream>>>(Whh_f, whhhi,          whhlo,          NG*EDIM);
    k_split<<<1024, 256, 0, stream>>>(Whh_b, whhhi + NG*EDIM, whhlo + NG*EDIM, NG*EDIM);
    k_gather<<<16384, 256, 0, stream>>>(sentence, embedding, ehi, elo);

    k_gemm<<<dim3(16, 128, 2), 512, 0, stream>>>(ehi, elo, wihhi, wihlo, b_f, b_b, X);

    hipFuncSetAttribute((const void*)k_rec, hipFuncAttributeMaxDynamicSharedMemorySize, 139776);
    k_rec<<<64, 512, 139776, stream>>>(X, whhhi, whhlo, hx, h_hist, cnt);

    k_feats<<<4096, 256, 0, stream>>>(h_hist, W_out, b_out, feats);
    k_viterbi<<<32, 64, 0, stream>>>(feats, trans, startt, stopt, (int*)d_out);
}

// Round 4
// 3424.824 us; speedup vs baseline: 1.0193x; 1.0193x over previous
//
#include <hip/hip_runtime.h>
#include <stdint.h>

#define BATCH 32
#define SEQ   512
#define EDIM  512
#define HID   512            // per-direction hidden
#define NG    2048           // 4*HID gate rows
#define NTAG  16

typedef _Float16 f16;
typedef _Float16 f16x4 __attribute__((ext_vector_type(4)));
typedef _Float16 f16x8 __attribute__((ext_vector_type(8)));
typedef float    f32x4 __attribute__((ext_vector_type(4)));

#define LO_SCALE 2048.0f
#define LO_INV   (1.0f/2048.0f)

// ---------------- prep: fp32 -> f16 hi/lo limb split (lo scaled by 2048) ---
__global__ __launch_bounds__(256) void k_split(const float* __restrict__ src,
                                               f16* __restrict__ hi, f16* __restrict__ lo, int n) {
    int i = blockIdx.x * blockDim.x + threadIdx.x;
    int stride = gridDim.x * blockDim.x;
    for (; i < n; i += stride) {
        float x = src[i];
        f16 h = (f16)x;
        hi[i] = h;
        lo[i] = (f16)((x - (float)h) * LO_SCALE);
    }
}

// ---------------- gather embedding rows + split -----------------------------
__global__ __launch_bounds__(256) void k_gather(const int* __restrict__ sent,
                                                const float* __restrict__ emb,
                                                f16* __restrict__ ehi, f16* __restrict__ elo) {
    int m = blockIdx.x;                  // 0..16383 = b*SEQ+s
    int idx = sent[m];
    const float* src = emb + (size_t)idx * EDIM;
    int k = threadIdx.x * 2;
    float2 v = *(const float2*)(src + k);
    f16 h0 = (f16)v.x, h1 = (f16)v.y;
    ehi[(size_t)m*EDIM + k]     = h0;
    ehi[(size_t)m*EDIM + k + 1] = h1;
    elo[(size_t)m*EDIM + k]     = (f16)((v.x - (float)h0) * LO_SCALE);
    elo[(size_t)m*EDIM + k + 1] = (f16)((v.y - (float)h1) * LO_SCALE);
}

__device__ __forceinline__ void gld16(const void* g, void* l) {
    __builtin_amdgcn_global_load_lds((const __attribute__((address_space(1))) uint32_t*)g,
                                     (__attribute__((address_space(3))) uint32_t*)l, 16, 0, 0);
}
__device__ __forceinline__ f32x4 mfma16(f16x8 a, f16x8 b, f32x4 c) {
    return __builtin_amdgcn_mfma_f32_16x16x32_f16(a, b, c, 0, 0, 0);
}

// ---------------- input projection: X = emb @ Wih^T + bias (f16x2 limbs) ----
__global__ __launch_bounds__(512, 2) void k_gemm(
    const f16* __restrict__ Ahi, const f16* __restrict__ Alo,    // [16384][512]
    const f16* __restrict__ Whi, const f16* __restrict__ Wlo,    // [2][2048][512]
    const float* __restrict__ bias_f, const float* __restrict__ bias_b,
    float* __restrict__ Xout)                                     // [2][16384][2048]
{
    const int n0  = blockIdx.x * 128;
    const int m0  = blockIdx.y * 128;
    const int dir = blockIdx.z;
    const float* bias = dir ? bias_b : bias_f;
    const f16* Bhi = Whi + (size_t)dir * NG * EDIM;
    const f16* Blo = Wlo + (size_t)dir * NG * EDIM;
    float* X = Xout + (size_t)dir * 16384 * NG;

    __shared__ f16 sAh[128*64], sAl[128*64], sBh[128*64], sBl[128*64];  // 64 KiB

    const int tid  = threadIdx.x;
    const int lane = tid & 63;
    const int wave = tid >> 6;        // 0..7
    const int wr   = wave >> 2;       // 0..1  (64 rows)
    const int wc   = wave & 3;        // 0..3  (32 cols)

    f32x4 accH[4][2] = {};
    f32x4 accM[4][2] = {};

    for (int kt = 0; kt < 8; ++kt) {
        const int kbase = kt * 64;
        for (int sub = 0; sub < 2; ++sub) {
            int byte = sub*8192 + tid*16;
            int row  = byte >> 7;          // 0..127
            int up   = (byte >> 4) & 7;
            int u    = up ^ (row & 7);     // logical 16B unit
            const f16* ga  = Ahi + (size_t)(m0 + row)*EDIM + kbase + u*8;
            const f16* gal = Alo + (size_t)(m0 + row)*EDIM + kbase + u*8;
            const f16* gb  = Bhi + (size_t)(n0 + row)*EDIM + kbase + u*8;
            const f16* gbl = Blo + (size_t)(n0 + row)*EDIM + kbase + u*8;
            gld16(ga,  (char*)sAh + byte);
            gld16(gal, (char*)sAl + byte);
            gld16(gb,  (char*)sBh + byte);
            gld16(gbl, (char*)sBl + byte);
        }
        __syncthreads();
        for (int ks = 0; ks < 2; ++ks) {
            f16x8 fAh[4], fAl[4], fBh[2], fBl[2];
            #pragma unroll
            for (int mi = 0; mi < 4; ++mi) {
                int row = wr*64 + mi*16 + (lane & 15);
                int u   = ks*4 + (lane >> 4);
                int off = row*128 + (u ^ (row & 7))*16;
                fAh[mi] = *(const f16x8*)((const char*)sAh + off);
                fAl[mi] = *(const f16x8*)((const char*)sAl + off);
            }
            #pragma unroll
            for (int ni = 0; ni < 2; ++ni) {
                int row = wc*32 + ni*16 + (lane & 15);
                int u   = ks*4 + (lane >> 4);
                int off = row*128 + (u ^ (row & 7))*16;
                fBh[ni] = *(const f16x8*)((const char*)sBh + off);
                fBl[ni] = *(const f16x8*)((const char*)sBl + off);
            }
            #pragma unroll
            for (int mi = 0; mi < 4; ++mi)
                #pragma unroll
                for (int ni = 0; ni < 2; ++ni)
                    accH[mi][ni] = mfma16(fAh[mi], fBh[ni], accH[mi][ni]);
            #pragma unroll
            for (int mi = 0; mi < 4; ++mi)
                #pragma unroll
                for (int ni = 0; ni < 2; ++ni)
                    accM[mi][ni] = mfma16(fAh[mi], fBl[ni], accM[mi][ni]);
            #pragma unroll
            for (int mi = 0; mi < 4; ++mi)
                #pragma unroll
                for (int ni = 0; ni < 2; ++ni)
                    accM[mi][ni] = mfma16(fAl[mi], fBh[ni], accM[mi][ni]);
        }
        __syncthreads();
    }
    #pragma unroll
    for (int ni = 0; ni < 2; ++ni) {
        int col = n0 + wc*32 + ni*16 + (lane & 15);
        float bv = bias[col];
        #pragma unroll
        for (int mi = 0; mi < 4; ++mi) {
            #pragma unroll
            for (int j = 0; j < 4; ++j) {
                int m = m0 + wr*64 + mi*16 + (lane >> 4)*4 + j;
                X[(size_t)m * NG + col] = accH[mi][ni][j] + accM[mi][ni][j]*LO_INV + bv;
            }
        }
    }
}

// ---------------- persistent bidirectional LSTM recurrence (v4) -------------
// 64 WGs: dir(2) x chunk(32, 16 hidden units => 64 gate rows).
// Flagless sync: every exchanged h-f32 carries a 2-bit step tag ((t>>1)&3)
// in its mantissa LSBs; consumers poll the data packets directly (sc1).
// Whh hi+lo fragments are step-invariant -> 128 VGPRs. LDS: h planes + gbuf.
__global__ __launch_bounds__(512, 1) void k_rec(
    const float* __restrict__ Xall,                               // [2][16384][2048]
    const f16* __restrict__ Whi, const f16* __restrict__ Wlo,     // [2][2048][512]
    unsigned* __restrict__ hx,                                    // [2][2][32][512] tagged f32
    float* __restrict__ h_hist)                                   // [16384][1024]
{
    extern __shared__ char smem[];
    char*  hhiS = smem;                       // h hi plane [32][64 x 16B] swizzled
    char*  hloS = smem + 32768;               // h lo plane
    float* gbuf = (float*)(smem + 65536);     // [4][32][17]

    const int wg    = blockIdx.x;
    const int dir   = wg >> 5;
    const int chunk = wg & 31;
    const int u0    = chunk * 16;
    const int tid   = threadIdx.x;
    const int lane  = tid & 63;
    const int wave  = tid >> 6;
    const int g     = wave >> 1;     // gate type i,f,g,o
    const int mt    = wave & 1;      // batch half

    const float* X = Xall + (size_t)dir * 16384 * NG;
    unsigned* hxd = hx + (size_t)dir * 2 * BATCH * HID;

    const int pb = tid >> 4;          // batch 0..31
    const int pu = tid & 15;          // hidden unit within chunk
    const int arow  = mt*16 + (lane & 15);
    const char* hrowH = hhiS + arow*1024;
    const char* hrowL = hloS + arow*1024;
    const int arow7 = arow & 7;

    // step-invariant Whh B-fragments -> registers (hi + lo, 128 VGPR)
    const int grow = g*512 + u0 + (lane & 15);
    const f16* bhP = Whi + ((size_t)(dir*NG + grow))*EDIM + (lane >> 4)*8;
    const f16* blP = Wlo + ((size_t)(dir*NG + grow))*EDIM + (lane >> 4)*8;
    f16x8 bhv[16], blv[16];
    #pragma unroll
    for (int kt = 0; kt < 16; ++kt) {
        bhv[kt] = *(const f16x8*)(bhP + kt*32);
        blv[kt] = *(const f16x8*)(blP + kt*32);
    }

    float c = 0.0f;                   // cell state for (pb,pu)

    for (int t = 0; t < SEQ; ++t) {
        const int s = dir ? (SEQ - 1 - t) : t;

        // X prefetch (latency hides under poll)
        float xv[4];
        {
            int col = g*512 + u0 + (lane & 15);
            #pragma unroll
            for (int j = 0; j < 4; ++j) {
                int batch = mt*16 + (lane >> 4)*4 + j;
                xv[j] = X[((size_t)batch*SEQ + s)*NG + col];
            }
        }

        // fill h planes (poll data packets for this step's tag)
        if (t == 0) {
            #pragma unroll
            for (int i = 0; i < 8; ++i) {
                int q = i*512 + tid, batch = q >> 7, kq = (q & 127)*4;
                int off = batch*1024 + ((kq >> 3) ^ (batch & 7))*16 + (kq & 7)*2;
                *(f16x4*)(hhiS + off) = (f16x4){(f16)0.f,(f16)0.f,(f16)0.f,(f16)0.f};
                *(f16x4*)(hloS + off) = (f16x4){(f16)0.f,(f16)0.f,(f16)0.f,(f16)0.f};
            }
        } else {
            const unsigned tag = (unsigned)((t - 1) >> 1) & 3u;
            const unsigned* hsrc = hxd + (size_t)(t & 1) * BATCH * HID;
            unsigned pend = 0xffu;
            while (pend) {
                unsigned long long va[8], vb[8];
                #pragma unroll
                for (int i = 0; i < 8; ++i) {
                    if (pend & (1u << i)) {
                        int q = i*512 + tid;
                        const unsigned long long* p =
                            (const unsigned long long*)(hsrc + (q >> 7)*HID + (q & 127)*4);
                        va[i] = __hip_atomic_load(p,     __ATOMIC_RELAXED, __HIP_MEMORY_SCOPE_AGENT);
                        vb[i] = __hip_atomic_load(p + 1, __ATOMIC_RELAXED, __HIP_MEMORY_SCOPE_AGENT);
                    }
                }
                #pragma unroll
                for (int i = 0; i < 8; ++i) {
                    if (!(pend & (1u << i))) continue;
                    unsigned w0 = (unsigned)va[i], w1 = (unsigned)(va[i] >> 32);
                    unsigned w2 = (unsigned)vb[i], w3 = (unsigned)(vb[i] >> 32);
                    if ((((w0 ^ tag) | (w1 ^ tag) | (w2 ^ tag) | (w3 ^ tag)) & 3u) != 0u)
                        continue;   // not all words carry this step's tag yet
                    float f0 = __builtin_bit_cast(float, w0);
                    float f1 = __builtin_bit_cast(float, w1);
                    float f2 = __builtin_bit_cast(float, w2);
                    float f3 = __builtin_bit_cast(float, w3);
                    f16 h0 = (f16)f0, h1 = (f16)f1, h2 = (f16)f2, h3 = (f16)f3;
                    f16x4 vh = {h0, h1, h2, h3};
                    f16x4 vl = {(f16)((f0 - (float)h0) * LO_SCALE),
                                (f16)((f1 - (float)h1) * LO_SCALE),
                                (f16)((f2 - (float)h2) * LO_SCALE),
                                (f16)((f3 - (float)h3) * LO_SCALE)};
                    int q = i*512 + tid, batch = q >> 7, kq = (q & 127)*4;
                    int off = batch*1024 + ((kq >> 3) ^ (batch & 7))*16 + (kq & 7)*2;
                    *(f16x4*)(hhiS + off) = vh;
                    *(f16x4*)(hloS + off) = vl;
                    pend &= ~(1u << i);
                }
                if (pend) __builtin_amdgcn_s_sleep(1);
            }
        }
        __syncthreads();                       // (2) fill done

        // MFMA: gates = h @ Whh^T (+X preloaded into acc)
        f32x4 aH[2], aMa[2], aMb[2];
        aH[0] = (f32x4){xv[0], xv[1], xv[2], xv[3]};
        aH[1] = (f32x4){0.f, 0.f, 0.f, 0.f};
        aMa[0] = aH[1]; aMa[1] = aH[1]; aMb[0] = aH[1]; aMb[1] = aH[1];
        #pragma unroll
        for (int kt = 0; kt < 16; ++kt) {
            int ug = kt*4 + (lane >> 4);
            f16x8 ah = *(const f16x8*)(hrowH + (ug ^ arow7)*16);
            f16x8 al = *(const f16x8*)(hrowL + (ug ^ arow7)*16);
            aH [kt & 1] = mfma16(ah, bhv[kt], aH [kt & 1]);
            aMa[kt & 1] = mfma16(ah, blv[kt], aMa[kt & 1]);
            aMb[kt & 1] = mfma16(al, bhv[kt], aMb[kt & 1]);
        }
        f32x4 rH = aH[0] + aH[1];
        f32x4 rM = aMa[0] + aMa[1] + aMb[0] + aMb[1];
        #pragma unroll
        for (int j = 0; j < 4; ++j) {
            int batch = mt*16 + (lane >> 4)*4 + j;
            gbuf[(g*BATCH + batch)*17 + (lane & 15)] = rH[j] + rM[j]*LO_INV;
        }
        __syncthreads();                       // (3) gbuf ready; MFMA reads done

        // pointwise LSTM cell + tagged store (no drain: consumers poll data)
        {
            float iv = gbuf[(0*BATCH + pb)*17 + pu];
            float fv = gbuf[(1*BATCH + pb)*17 + pu];
            float gv = gbuf[(2*BATCH + pb)*17 + pu];
            float ov = gbuf[(3*BATCH + pb)*17 + pu];
            float si = 1.0f / (1.0f + expf(-iv));
            float sf = 1.0f / (1.0f + expf(-fv));
            float so = 1.0f / (1.0f + expf(-ov));
            c = sf * c + si * tanhf(gv);
            float hval = so * tanhf(c);
            unsigned hb = (__builtin_bit_cast(unsigned, hval) & ~3u) | ((unsigned)(t >> 1) & 3u);
            unsigned* hdst = hxd + (size_t)((t + 1) & 1)*BATCH*HID + pb*HID + u0 + pu;
            __hip_atomic_store(hdst, hb, __ATOMIC_RELAXED, __HIP_MEMORY_SCOPE_AGENT);
            h_hist[((size_t)pb*SEQ + s)*1024 + dir*HID + u0 + pu] = __builtin_bit_cast(float, hb);
        }
    }
}

// ---------------- output projection: feats = H @ W_out^T + b_out ------------
__global__ __launch_bounds__(256) void k_feats(
    const float* __restrict__ H,      // [16384][1024]
    const float* __restrict__ Wout,   // [16][1024]
    const float* __restrict__ bout,   // [16]
    float* __restrict__ feats)        // [16384][16]
{
    __shared__ float Wt[1024][16];    // 64 KiB, transposed
    int tid = threadIdx.x;
    for (int i = tid; i < 16384; i += 256)
        Wt[i >> 4][i & 15] = Wout[(i & 15)*1024 + (i >> 4)];
    __syncthreads();
    int wave = tid >> 6, lane = tid & 63;
    int row = blockIdx.x * 4 + wave;
    const float* hrow = H + (size_t)row * 1024;
    float acc[16];
    #pragma unroll
    for (int t = 0; t < 16; ++t) acc[t] = 0.f;
    #pragma unroll
    for (int cc = 0; cc < 4; ++cc) {
        float4 hv = *(const float4*)(hrow + cc*256 + lane*4);
        #pragma unroll
        for (int j = 0; j < 4; ++j) {
            int k = cc*256 + lane*4 + j;
            float h = (&hv.x)[j];
            #pragma unroll
            for (int tg = 0; tg < 16; ++tg) acc[tg] += h * Wt[k][tg];
        }
    }
    #pragma unroll
    for (int off = 32; off >= 1; off >>= 1) {
        #pragma unroll
        for (int tg = 0; tg < 16; ++tg) acc[tg] += __shfl_xor(acc[tg], off);
    }
    if (lane == 0) {
        #pragma unroll
        for (int tg = 0; tg < 16; ++tg)
            feats[(size_t)row*16 + tg] = acc[tg] + bout[tg];
    }
}

// ---------------- Viterbi + backtrace (one wave per batch) ------------------
__global__ __launch_bounds__(64) void k_viterbi(
    const float* __restrict__ feats,   // [32][512][16]
    const float* __restrict__ trans,   // [16][16] trans[prev][cur]
    const float* __restrict__ startt, const float* __restrict__ stopt,
    int* __restrict__ out)             // [32][512]
{
    __shared__ unsigned char bp[511*16];
    int b = blockIdx.x;
    int lane = threadIdx.x;
    int cur = lane & 15;
    int q   = lane >> 4;
    float tr[4];
    #pragma unroll
    for (int i = 0; i < 4; ++i) tr[i] = trans[(q*4 + i)*16 + cur];
    const float* fb = feats + (size_t)b * SEQ * NTAG;
    float v = fb[cur] + startt[cur];
    for (int s = 1; s < SEQ; ++s) {
        float best = -1e30f; int bi = 0;
        #pragma unroll
        for (int i = 0; i < 4; ++i) {
            float pv = __shfl(v, q*4 + i);
            float sc = pv + tr[i];
            if (sc > best) { best = sc; bi = q*4 + i; }   // first-max within quarter
        }
        #pragma unroll
        for (int off = 16; off <= 32; off <<= 1) {
            float ob = __shfl_xor(best, off);
            int   oi = __shfl_xor(bi, off);
            if (ob > best || (ob == best && oi < bi)) { best = ob; bi = oi; }
        }
        if (lane < 16) bp[(s - 1)*16 + cur] = (unsigned char)bi;
        v = best + fb[s*16 + cur];
    }
    float sc = v + stopt[cur];
    int bc = cur;
    #pragma unroll
    for (int off = 1; off <= 32; off <<= 1) {
        float os = __shfl_xor(sc, off);
        int   oc = __shfl_xor(bc, off);
        if (os > sc || (os == sc && oc < bc)) { sc = os; bc = oc; }
    }
    __syncthreads();
    if (lane == 0) {
        int curt = bc;
        out[b*SEQ + SEQ - 1] = curt;
        for (int s2 = SEQ - 2; s2 >= 0; --s2) {
            curt = bp[s2*16 + curt];
            out[b*SEQ + s2] = curt;
        }
    }
}

// ---------------- launch ----------------------------------------------------
extern "C" void kernel_launch(void* const* d_in, const int* in_sizes, int n_in,
                              void* d_out, int out_size, void* d_ws, size_t ws_size,
                              hipStream_t stream) {
    (void)in_sizes; (void)n_in; (void)out_size; (void)ws_size;
    const int*   sentence  = (const int*)  d_in[0];
    const float* embedding = (const float*)d_in[1];
    const float* Wih_f = (const float*)d_in[2];
    const float* Whh_f = (const float*)d_in[3];
    const float* b_f   = (const float*)d_in[4];
    const float* Wih_b = (const float*)d_in[5];
    const float* Whh_b = (const float*)d_in[6];
    const float* b_b   = (const float*)d_in[7];
    const float* W_out = (const float*)d_in[8];
    const float* b_out = (const float*)d_in[9];
    const float* trans = (const float*)d_in[10];
    const float* startt= (const float*)d_in[11];
    const float* stopt = (const float*)d_in[12];

    char* ws = (char*)d_ws;
    float* X      = (float*)(ws);                           // 268,435,456 B  [2][16384][2048]
    float* h_hist = (float*)(ws + 268435456ull);            //  67,108,864 B  [16384][1024]
    f16*   ehi    = (f16*)  (ws + 335544320ull);            //  16,777,216 B
    f16*   elo    = (f16*)  (ws + 352321536ull);            //  16,777,216 B
    f16*   wihhi  = (f16*)  (ws + 369098752ull);            //   4,194,304 B
    f16*   wihlo  = (f16*)  (ws + 373293056ull);
    f16*   whhhi  = (f16*)  (ws + 377487360ull);
    f16*   whhlo  = (f16*)  (ws + 381681664ull);
    unsigned* hx  = (unsigned*)(ws + 385875968ull);         //     262,144 B  [2][2][32][512]
    float* feats  = (float*)(ws + 386138112ull);            //   1,048,576 B

    // init exchange buffers to tag=3 pattern (never matches first 6 steps' tags)
    hipMemsetAsync(hx, 0x03, 262144, stream);

    k_split<<<1024, 256, 0, stream>>>(Wih_f, wihhi,          wihlo,          NG*EDIM);
    k_split<<<1024, 256, 0, stream>>>(Wih_b, wihhi + NG*EDIM, wihlo + NG*EDIM, NG*EDIM);
    k_split<<<1024, 256, 0, stream>>>(Whh_f, whhhi,          whhlo,          NG*EDIM);
    k_split<<<1024, 256, 0, stream>>>(Whh_b, whhhi + NG*EDIM, whhlo + NG*EDIM, NG*EDIM);
    k_gather<<<16384, 256, 0, stream>>>(sentence, embedding, ehi, elo);

    k_gemm<<<dim3(16, 128, 2), 512, 0, stream>>>(ehi, elo, wihhi, wihlo, b_f, b_b, X);

    hipFuncSetAttribute((const void*)k_rec, hipFuncAttributeMaxDynamicSharedMemorySize, 74240);
    k_rec<<<64, 512, 74240, stream>>>(X, whhhi, whhlo, hx, h_hist);

    k_feats<<<4096, 256, 0, stream>>>(h_hist, W_out, b_out, feats);
    k_viterbi<<<32, 64, 0, stream>>>(feats, trans, startt, stopt, (int*)d_out);
}

// Round 5
// 2860.697 us; speedup vs baseline: 1.2203x; 1.1972x over previous
//
#include <hip/hip_runtime.h>
#include <stdint.h>

#define BATCH 32
#define SEQ   512
#define EDIM  512
#define HID   512            // per-direction hidden
#define NG    2048           // 4*HID gate rows
#define NTAG  16

typedef _Float16 f16;
typedef _Float16 f16x4 __attribute__((ext_vector_type(4)));
typedef _Float16 f16x8 __attribute__((ext_vector_type(8)));
typedef float    f32x4 __attribute__((ext_vector_type(4)));

#define LO_SCALE 2048.0f
#define LO_INV   (1.0f/2048.0f)

// ---------------- prep: fp32 -> f16 hi/lo limb split (lo scaled by 2048) ---
__global__ __launch_bounds__(256) void k_split(const float* __restrict__ src,
                                               f16* __restrict__ hi, f16* __restrict__ lo, int n) {
    int i = blockIdx.x * blockDim.x + threadIdx.x;
    int stride = gridDim.x * blockDim.x;
    for (; i < n; i += stride) {
        float x = src[i];
        f16 h = (f16)x;
        hi[i] = h;
        lo[i] = (f16)((x - (float)h) * LO_SCALE);
    }
}

// ---------------- gather embedding rows + split -----------------------------
__global__ __launch_bounds__(256) void k_gather(const int* __restrict__ sent,
                                                const float* __restrict__ emb,
                                                f16* __restrict__ ehi, f16* __restrict__ elo) {
    int m = blockIdx.x;                  // 0..16383 = b*SEQ+s
    int idx = sent[m];
    const float* src = emb + (size_t)idx * EDIM;
    int k = threadIdx.x * 2;
    float2 v = *(const float2*)(src + k);
    f16 h0 = (f16)v.x, h1 = (f16)v.y;
    ehi[(size_t)m*EDIM + k]     = h0;
    ehi[(size_t)m*EDIM + k + 1] = h1;
    elo[(size_t)m*EDIM + k]     = (f16)((v.x - (float)h0) * LO_SCALE);
    elo[(size_t)m*EDIM + k + 1] = (f16)((v.y - (float)h1) * LO_SCALE);
}

__device__ __forceinline__ void gld16(const void* g, void* l) {
    __builtin_amdgcn_global_load_lds((const __attribute__((address_space(1))) uint32_t*)g,
                                     (__attribute__((address_space(3))) uint32_t*)l, 16, 0, 0);
}
__device__ __forceinline__ f32x4 mfma16(f16x8 a, f16x8 b, f32x4 c) {
    return __builtin_amdgcn_mfma_f32_16x16x32_f16(a, b, c, 0, 0, 0);
}

// ---------------- input projection: X = emb @ Wih^T + bias (f16x2 limbs) ----
__global__ __launch_bounds__(512, 2) void k_gemm(
    const f16* __restrict__ Ahi, const f16* __restrict__ Alo,    // [16384][512]
    const f16* __restrict__ Whi, const f16* __restrict__ Wlo,    // [2][2048][512]
    const float* __restrict__ bias_f, const float* __restrict__ bias_b,
    float* __restrict__ Xout)                                     // [2][16384][2048]
{
    const int n0  = blockIdx.x * 128;
    const int m0  = blockIdx.y * 128;
    const int dir = blockIdx.z;
    const float* bias = dir ? bias_b : bias_f;
    const f16* Bhi = Whi + (size_t)dir * NG * EDIM;
    const f16* Blo = Wlo + (size_t)dir * NG * EDIM;
    float* X = Xout + (size_t)dir * 16384 * NG;

    __shared__ f16 sAh[128*64], sAl[128*64], sBh[128*64], sBl[128*64];  // 64 KiB

    const int tid  = threadIdx.x;
    const int lane = tid & 63;
    const int wave = tid >> 6;        // 0..7
    const int wr   = wave >> 2;       // 0..1  (64 rows)
    const int wc   = wave & 3;        // 0..3  (32 cols)

    f32x4 accH[4][2] = {};
    f32x4 accM[4][2] = {};

    for (int kt = 0; kt < 8; ++kt) {
        const int kbase = kt * 64;
        for (int sub = 0; sub < 2; ++sub) {
            int byte = sub*8192 + tid*16;
            int row  = byte >> 7;          // 0..127
            int up   = (byte >> 4) & 7;
            int u    = up ^ (row & 7);     // logical 16B unit
            const f16* ga  = Ahi + (size_t)(m0 + row)*EDIM + kbase + u*8;
            const f16* gal = Alo + (size_t)(m0 + row)*EDIM + kbase + u*8;
            const f16* gb  = Bhi + (size_t)(n0 + row)*EDIM + kbase + u*8;
            const f16* gbl = Blo + (size_t)(n0 + row)*EDIM + kbase + u*8;
            gld16(ga,  (char*)sAh + byte);
            gld16(gal, (char*)sAl + byte);
            gld16(gb,  (char*)sBh + byte);
            gld16(gbl, (char*)sBl + byte);
        }
        __syncthreads();
        for (int ks = 0; ks < 2; ++ks) {
            f16x8 fAh[4], fAl[4], fBh[2], fBl[2];
            #pragma unroll
            for (int mi = 0; mi < 4; ++mi) {
                int row = wr*64 + mi*16 + (lane & 15);
                int u   = ks*4 + (lane >> 4);
                int off = row*128 + (u ^ (row & 7))*16;
                fAh[mi] = *(const f16x8*)((const char*)sAh + off);
                fAl[mi] = *(const f16x8*)((const char*)sAl + off);
            }
            #pragma unroll
            for (int ni = 0; ni < 2; ++ni) {
                int row = wc*32 + ni*16 + (lane & 15);
                int u   = ks*4 + (lane >> 4);
                int off = row*128 + (u ^ (row & 7))*16;
                fBh[ni] = *(const f16x8*)((const char*)sBh + off);
                fBl[ni] = *(const f16x8*)((const char*)sBl + off);
            }
            #pragma unroll
            for (int mi = 0; mi < 4; ++mi)
                #pragma unroll
                for (int ni = 0; ni < 2; ++ni)
                    accH[mi][ni] = mfma16(fAh[mi], fBh[ni], accH[mi][ni]);
            #pragma unroll
            for (int mi = 0; mi < 4; ++mi)
                #pragma unroll
                for (int ni = 0; ni < 2; ++ni)
                    accM[mi][ni] = mfma16(fAh[mi], fBl[ni], accM[mi][ni]);
            #pragma unroll
            for (int mi = 0; mi < 4; ++mi)
                #pragma unroll
                for (int ni = 0; ni < 2; ++ni)
                    accM[mi][ni] = mfma16(fAl[mi], fBh[ni], accM[mi][ni]);
        }
        __syncthreads();
    }
    #pragma unroll
    for (int ni = 0; ni < 2; ++ni) {
        int col = n0 + wc*32 + ni*16 + (lane & 15);
        float bv = bias[col];
        #pragma unroll
        for (int mi = 0; mi < 4; ++mi) {
            #pragma unroll
            for (int j = 0; j < 4; ++j) {
                int m = m0 + wr*64 + mi*16 + (lane >> 4)*4 + j;
                X[(size_t)m * NG + col] = accH[mi][ni][j] + accM[mi][ni][j]*LO_INV + bv;
            }
        }
    }
}

// ---------------- persistent bidirectional LSTM recurrence (v5) -------------
// 64 WGs: dir(2) x chunk(32, 16 hidden units => 64 gate rows).
// Wave tiling (mt, g2, kh): 2 batch-blocks x 2 gate-pair-blocks x 2 K-halves
//   -> A(h) LDS reads halved; B(Whh limbs) in registers; kh-partials via gbuf.
// Exchange: packed u32 = f16 hi | f16 lo<<16, 2-bit step tag in lo mantissa
//   LSBs (bits 17:16); consumers poll the data itself (sc1, no flags).
__global__ __launch_bounds__(512, 1) void k_rec(
    const float* __restrict__ Xall,                               // [2][16384][2048]
    const f16* __restrict__ Whi, const f16* __restrict__ Wlo,     // [2][2048][512]
    unsigned* __restrict__ hx,                                    // [2][2][32][512] packed
    float* __restrict__ h_hist)                                   // [16384][1024]
{
    extern __shared__ char smem[];
    char*  hhiS = smem;                       // h hi plane [32][64 x 16B] swizzled
    char*  hloS = smem + 32768;               // h lo plane
    float* gbuf = (float*)(smem + 65536);     // [2][4*32*17]

    const int wg    = blockIdx.x;
    const int dir   = wg >> 5;
    const int chunk = wg & 31;
    const int u0    = chunk * 16;
    const int tid   = threadIdx.x;
    const int lane  = tid & 63;
    const int wave  = tid >> 6;
    const int mt    = wave & 1;        // batch half
    const int kh    = (wave >> 1) & 1; // K half
    const int g2    = wave >> 2;       // gate-pair block (gates 2*g2, 2*g2+1)
    const int u     = lane & 15;
    const int q4    = lane >> 4;

    const float* X = Xall + (size_t)dir * 16384 * NG;
    unsigned* hxd = hx + (size_t)dir * 2 * BATCH * HID;

    const int pb = tid >> 4;          // batch 0..31 (cell thread)
    const int pu = tid & 15;          // hidden unit within chunk (cell thread)
    const int arow  = mt*16 + u;      // A batch row
    const char* hrowH = hhiS + arow*1024;
    const char* hrowL = hloS + arow*1024;
    const int arow7 = arow & 7;

    // step-invariant Whh B-fragments -> registers (2 gates x 8 kt x hi/lo)
    f16x8 bhv[2][8], blv[2][8];
    #pragma unroll
    for (int gt = 0; gt < 2; ++gt) {
        const size_t row = (size_t)(dir*NG + (g2*2 + gt)*512 + u0 + u) * EDIM;
        const f16* ph = Whi + row + q4*8;
        const f16* pl = Wlo + row + q4*8;
        #pragma unroll
        for (int kt = 0; kt < 8; ++kt) {
            bhv[gt][kt] = *(const f16x8*)(ph + (kh*8 + kt)*32);
            blv[gt][kt] = *(const f16x8*)(pl + (kh*8 + kt)*32);
        }
    }

    float c = 0.0f;                   // cell state for (pb,pu)

    for (int t = 0; t < SEQ; ++t) {
        const int s = dir ? (SEQ - 1 - t) : t;

        // X prefetch for the cell phase (latency hides under poll+MFMA)
        float xv[4];
        {
            const float* xb = X + ((size_t)pb*SEQ + s)*NG + u0 + pu;
            #pragma unroll
            for (int g = 0; g < 4; ++g) xv[g] = xb[g*512];
        }

        // fill h planes (poll packed data for this step's tag)
        if (t == 0) {
            #pragma unroll
            for (int i = 0; i < 8; ++i) {
                int q = i*512 + tid, batch = q >> 7, kq = (q & 127)*4;
                int off = batch*1024 + ((kq >> 3) ^ (batch & 7))*16 + (kq & 4)*2;
                *(uint2*)(hhiS + off) = (uint2){0u, 0u};
                *(uint2*)(hloS + off) = (uint2){0u, 0u};
            }
        } else {
            const unsigned tag32 = ((unsigned)((t - 1) >> 1) & 3u) << 16;
            const unsigned* hsrc = hxd + (size_t)(t & 1) * BATCH * HID;
            unsigned pend = 0xffu;
            while (pend) {
                unsigned long long va[8], vb[8];
                #pragma unroll
                for (int i = 0; i < 8; ++i) {
                    if (pend & (1u << i)) {
                        int q = i*512 + tid;
                        const unsigned long long* p =
                            (const unsigned long long*)(hsrc + (q >> 7)*HID + (q & 127)*4);
                        va[i] = __hip_atomic_load(p,     __ATOMIC_RELAXED, __HIP_MEMORY_SCOPE_AGENT);
                        vb[i] = __hip_atomic_load(p + 1, __ATOMIC_RELAXED, __HIP_MEMORY_SCOPE_AGENT);
                    }
                }
                #pragma unroll
                for (int i = 0; i < 8; ++i) {
                    if (!(pend & (1u << i))) continue;
                    unsigned w0 = (unsigned)va[i], w1 = (unsigned)(va[i] >> 32);
                    unsigned w2 = (unsigned)vb[i], w3 = (unsigned)(vb[i] >> 32);
                    if ((((w0 ^ tag32) | (w1 ^ tag32) | (w2 ^ tag32) | (w3 ^ tag32)) & 0x30000u) != 0u)
                        continue;   // not all words carry this step's tag yet
                    unsigned hi01 = (w0 & 0xffffu) | (w1 << 16);
                    unsigned hi23 = (w2 & 0xffffu) | (w3 << 16);
                    unsigned lo01 = (w0 >> 16) | (w1 & 0xffff0000u);
                    unsigned lo23 = (w2 >> 16) | (w3 & 0xffff0000u);
                    int q = i*512 + tid, batch = q >> 7, kq = (q & 127)*4;
                    int off = batch*1024 + ((kq >> 3) ^ (batch & 7))*16 + (kq & 4)*2;
                    *(uint2*)(hhiS + off) = (uint2){hi01, hi23};
                    *(uint2*)(hloS + off) = (uint2){lo01, lo23};
                    pend &= ~(1u << i);
                }
                if (pend) __builtin_amdgcn_s_sleep(1);
            }
        }
        __syncthreads();                       // (1) fill done

        // MFMA: partial gates = h @ Whh^T for this wave's (mt, g2, kh)
        f32x4 accH[2] = {}, accMa[2] = {}, accMb[2] = {};
        #pragma unroll
        for (int kt = 0; kt < 8; ++kt) {
            int ug = (kh*8 + kt)*4 + q4;
            f16x8 ah = *(const f16x8*)(hrowH + (ug ^ arow7)*16);
            f16x8 al = *(const f16x8*)(hrowL + (ug ^ arow7)*16);
            #pragma unroll
            for (int gt = 0; gt < 2; ++gt) {
                accH[gt]  = mfma16(ah, bhv[gt][kt], accH[gt]);
                accMa[gt] = mfma16(ah, blv[gt][kt], accMa[gt]);
                accMb[gt] = mfma16(al, bhv[gt][kt], accMb[gt]);
            }
        }
        #pragma unroll
        for (int gt = 0; gt < 2; ++gt) {
            f32x4 rH = accH[gt];
            f32x4 rM = accMa[gt] + accMb[gt];
            #pragma unroll
            for (int j = 0; j < 4; ++j) {
                int row = (g2*2 + gt)*32 + mt*16 + q4*4 + j;   // gtype*32 + batch
                gbuf[kh*2176 + row*17 + u] = rH[j] + rM[j]*LO_INV;
            }
        }
        __syncthreads();                       // (2) gbuf ready; plane reads done

        // pointwise LSTM cell + packed tagged store
        {
            float gs[4];
            #pragma unroll
            for (int g = 0; g < 4; ++g)
                gs[g] = gbuf[(g*32 + pb)*17 + pu] + gbuf[2176 + (g*32 + pb)*17 + pu] + xv[g];
            float si = 1.0f / (1.0f + __expf(-gs[0]));
            float sf = 1.0f / (1.0f + __expf(-gs[1]));
            float tg = 1.0f - 2.0f / (__expf(2.0f*gs[2]) + 1.0f);
            float so = 1.0f / (1.0f + __expf(-gs[3]));
            c = sf * c + si * tg;
            float hval = so * (1.0f - 2.0f / (__expf(2.0f*c) + 1.0f));
            f16 hh = (f16)hval;
            f16 hl = (f16)((hval - (float)hh) * LO_SCALE);
            unsigned packed = (unsigned)__builtin_bit_cast(unsigned short, hh)
                            | ((unsigned)__builtin_bit_cast(unsigned short, hl) << 16);
            packed = (packed & ~0x30000u) | ((((unsigned)t >> 1) & 3u) << 16);
            unsigned* hdst = hxd + (size_t)((t + 1) & 1)*BATCH*HID + pb*HID + u0 + pu;
            __hip_atomic_store(hdst, packed, __ATOMIC_RELAXED, __HIP_MEMORY_SCOPE_AGENT);
            // h_hist off the critical path (plain store, drains under next poll)
            h_hist[((size_t)pb*SEQ + s)*1024 + dir*HID + u0 + pu] = hval;
        }
    }
}

// ---------------- output projection: feats = H @ W_out^T + b_out ------------
__global__ __launch_bounds__(256) void k_feats(
    const float* __restrict__ H,      // [16384][1024]
    const float* __restrict__ Wout,   // [16][1024]
    const float* __restrict__ bout,   // [16]
    float* __restrict__ feats)        // [16384][16]
{
    __shared__ float Wt[1024][16];    // 64 KiB, transposed
    int tid = threadIdx.x;
    for (int i = tid; i < 16384; i += 256)
        Wt[i >> 4][i & 15] = Wout[(i & 15)*1024 + (i >> 4)];
    __syncthreads();
    int wave = tid >> 6, lane = tid & 63;
    int row = blockIdx.x * 4 + wave;
    const float* hrow = H + (size_t)row * 1024;
    float acc[16];
    #pragma unroll
    for (int t = 0; t < 16; ++t) acc[t] = 0.f;
    #pragma unroll
    for (int cc = 0; cc < 4; ++cc) {
        float4 hv = *(const float4*)(hrow + cc*256 + lane*4);
        #pragma unroll
        for (int j = 0; j < 4; ++j) {
            int k = cc*256 + lane*4 + j;
            float h = (&hv.x)[j];
            #pragma unroll
            for (int tg = 0; tg < 16; ++tg) acc[tg] += h * Wt[k][tg];
        }
    }
    #pragma unroll
    for (int off = 32; off >= 1; off >>= 1) {
        #pragma unroll
        for (int tg = 0; tg < 16; ++tg) acc[tg] += __shfl_xor(acc[tg], off);
    }
    if (lane == 0) {
        #pragma unroll
        for (int tg = 0; tg < 16; ++tg)
            feats[(size_t)row*16 + tg] = acc[tg] + bout[tg];
    }
}

// ---------------- Viterbi + backtrace (one wave per batch) ------------------
__global__ __launch_bounds__(64) void k_viterbi(
    const float* __restrict__ feats,   // [32][512][16]
    const float* __restrict__ trans,   // [16][16] trans[prev][cur]
    const float* __restrict__ startt, const float* __restrict__ stopt,
    int* __restrict__ out)             // [32][512]
{
    __shared__ unsigned char bp[511*16];
    int b = blockIdx.x;
    int lane = threadIdx.x;
    int cur = lane & 15;
    int q   = lane >> 4;
    float tr[4];
    #pragma unroll
    for (int i = 0; i < 4; ++i) tr[i] = trans[(q*4 + i)*16 + cur];
    const float* fb = feats + (size_t)b * SEQ * NTAG;
    float v = fb[cur] + startt[cur];
    for (int s = 1; s < SEQ; ++s) {
        float best = -1e30f; int bi = 0;
        #pragma unroll
        for (int i = 0; i < 4; ++i) {
            float pv = __shfl(v, q*4 + i);
            float sc = pv + tr[i];
            if (sc > best) { best = sc; bi = q*4 + i; }   // first-max within quarter
        }
        #pragma unroll
        for (int off = 16; off <= 32; off <<= 1) {
            float ob = __shfl_xor(best, off);
            int   oi = __shfl_xor(bi, off);
            if (ob > best || (ob == best && oi < bi)) { best = ob; bi = oi; }
        }
        if (lane < 16) bp[(s - 1)*16 + cur] = (unsigned char)bi;
        v = best + fb[s*16 + cur];
    }
    float sc = v + stopt[cur];
    int bc = cur;
    #pragma unroll
    for (int off = 1; off <= 32; off <<= 1) {
        float os = __shfl_xor(sc, off);
        int   oc = __shfl_xor(bc, off);
        if (os > sc || (os == sc && oc < bc)) { sc = os; bc = oc; }
    }
    __syncthreads();
    if (lane == 0) {
        int curt = bc;
        out[b*SEQ + SEQ - 1] = curt;
        for (int s2 = SEQ - 2; s2 >= 0; --s2) {
            curt = bp[s2*16 + curt];
            out[b*SEQ + s2] = curt;
        }
    }
}

// ---------------- launch ----------------------------------------------------
extern "C" void kernel_launch(void* const* d_in, const int* in_sizes, int n_in,
                              void* d_out, int out_size, void* d_ws, size_t ws_size,
                              hipStream_t stream) {
    (void)in_sizes; (void)n_in; (void)out_size; (void)ws_size;
    const int*   sentence  = (const int*)  d_in[0];
    const float* embedding = (const float*)d_in[1];
    const float* Wih_f = (const float*)d_in[2];
    const float* Whh_f = (const float*)d_in[3];
    const float* b_f   = (const float*)d_in[4];
    const float* Wih_b = (const float*)d_in[5];
    const float* Whh_b = (const float*)d_in[6];
    const float* b_b   = (const float*)d_in[7];
    const float* W_out = (const float*)d_in[8];
    const float* b_out = (const float*)d_in[9];
    const float* trans = (const float*)d_in[10];
    const float* startt= (const float*)d_in[11];
    const float* stopt = (const float*)d_in[12];

    char* ws = (char*)d_ws;
    float* X      = (float*)(ws);                           // 268,435,456 B  [2][16384][2048]
    float* h_hist = (float*)(ws + 268435456ull);            //  67,108,864 B  [16384][1024]
    f16*   ehi    = (f16*)  (ws + 335544320ull);            //  16,777,216 B
    f16*   elo    = (f16*)  (ws + 352321536ull);            //  16,777,216 B
    f16*   wihhi  = (f16*)  (ws + 369098752ull);            //   4,194,304 B
    f16*   wihlo  = (f16*)  (ws + 373293056ull);
    f16*   whhhi  = (f16*)  (ws + 377487360ull);
    f16*   whhlo  = (f16*)  (ws + 381681664ull);
    unsigned* hx  = (unsigned*)(ws + 385875968ull);         //     262,144 B  [2][2][32][512]
    float* feats  = (float*)(ws + 386138112ull);            //   1,048,576 B

    // init exchange buffers: tag field (bits 17:16) = 3, stale vs early tags
    hipMemsetAsync(hx, 0xFF, 262144, stream);

    k_split<<<1024, 256, 0, stream>>>(Wih_f, wihhi,          wihlo,          NG*EDIM);
    k_split<<<1024, 256, 0, stream>>>(Wih_b, wihhi + NG*EDIM, wihlo + NG*EDIM, NG*EDIM);
    k_split<<<1024, 256, 0, stream>>>(Whh_f, whhhi,          whhlo,          NG*EDIM);
    k_split<<<1024, 256, 0, stream>>>(Whh_b, whhhi + NG*EDIM, whhlo + NG*EDIM, NG*EDIM);
    k_gather<<<16384, 256, 0, stream>>>(sentence, embedding, ehi, elo);

    k_gemm<<<dim3(16, 128, 2), 512, 0, stream>>>(ehi, elo, wihhi, wihlo, b_f, b_b, X);

    hipFuncSetAttribute((const void*)k_rec, hipFuncAttributeMaxDynamicSharedMemorySize, 82944);
    k_rec<<<64, 512, 82944, stream>>>(X, whhhi, whhlo, hx, h_hist);

    k_feats<<<4096, 256, 0, stream>>>(h_hist, W_out, b_out, feats);
    k_viterbi<<<32, 64, 0, stream>>>(feats, trans, startt, stopt, (int*)d_out);
}